// Round 5
// baseline (640.484 us; speedup 1.0000x reference)
//
#include <hip/hip_runtime.h>
#include <hip/hip_bf16.h>

typedef unsigned short u16;
typedef unsigned int   u32;
typedef unsigned long long u64;
typedef __attribute__((ext_vector_type(8))) short bf16x8;
typedef __attribute__((ext_vector_type(4))) float f32x4;

#define NNODES 50000
#define PADM   50176          // 256 * 196

#define GAS __attribute__((address_space(1)))
#define LAS __attribute__((address_space(3)))

__device__ __forceinline__ u16 f32_bf16_rne(float x) {
    u32 u = __float_as_uint(x);
    return (u16)((u + 0x7fffu + ((u >> 16) & 1u)) >> 16);
}
__device__ __forceinline__ float bf16_f32(u16 h) {
    return __uint_as_float(((u32)h) << 16);
}
__device__ __forceinline__ void barx() {
    asm volatile("" ::: "memory");
    __builtin_amdgcn_s_barrier();
    asm volatile("" ::: "memory");
}

// ---------------- CSR build ----------------

__global__ void k_zero_cnt(int* __restrict__ cnt, int n) {
    int i = blockIdx.x * 256 + threadIdx.x;
    if (i < n) cnt[i] = 0;
}

__global__ void k_count(const int* __restrict__ dst, int E, int* __restrict__ cnt) {
    int e = blockIdx.x * 256 + threadIdx.x;
    if (e < E) atomicAdd(&cnt[dst[e]], 1);
}

__global__ void k_dinv(const int* __restrict__ cnt, float* __restrict__ dinv, int n) {
    int i = blockIdx.x * 256 + threadIdx.x;
    if (i < n) dinv[i] = rsqrtf((float)(cnt[i] + 1));   // +1 self loop
}

__global__ __launch_bounds__(1024) void k_scan(const int* __restrict__ cnt, int n,
                                               int* __restrict__ offs, int* __restrict__ cursor) {
    __shared__ int sums[1024];
    int t = threadIdx.x;
    int per = (n + 1023) / 1024;
    int start = t * per;
    int end = start + per; if (end > n) end = n;
    int s = 0;
    for (int i = start; i < end; ++i) s += cnt[i];
    sums[t] = s;
    __syncthreads();
    for (int d = 1; d < 1024; d <<= 1) {
        int v = (t >= d) ? sums[t - d] : 0;
        __syncthreads();
        sums[t] += v;
        __syncthreads();
    }
    int base = (t == 0) ? 0 : sums[t - 1];
    for (int i = start; i < end; ++i) {
        offs[i] = base; cursor[i] = base;
        base += cnt[i];
    }
    if (t == 1023) offs[n] = sums[1023];
}

__global__ void k_fill(const int* __restrict__ src, const int* __restrict__ dst, int E,
                       int* __restrict__ cursor, const float* __restrict__ dinv,
                       int* __restrict__ csr_src, float* __restrict__ csr_w) {
    int e = blockIdx.x * 256 + threadIdx.x;
    if (e < E) {
        int s = src[e], d = dst[e];
        int slot = atomicAdd(&cursor[d], 1);
        csr_src[slot] = s;
        csr_w[slot] = dinv[s] * dinv[d];
    }
}

// ---------------- weight split: W[N][K] f32 -> [N][2K] bf16 [hi|lo] ----------------

__global__ void k_splitW(const float* __restrict__ W, u16* __restrict__ W2, int total, int K) {
    int i = blockIdx.x * 256 + threadIdx.x;
    if (i >= total) return;
    int n = i / K, k = i - n * K;
    float w = W[i];
    u16 hi = f32_bf16_rne(w);
    u16 lo = f32_bf16_rne(w - bf16_f32(hi));
    W2[(size_t)n * (2 * K) + k] = hi;
    W2[(size_t)n * (2 * K) + K + k] = lo;
}

// ---------------- aggregation: 32 lanes/node, 2 nodes/wave, 4 rows in flight ----------------

template <int C>   // 128 or 256
__global__ __launch_bounds__(256) void k_aggregate_split(
    const float* __restrict__ x,
    const int* __restrict__ offs,
    const int* __restrict__ csr_src,
    const float* __restrict__ csr_w,
    const float* __restrict__ dinv,
    u16* __restrict__ out2,            // [PADM][2C] bf16 [hi(C)|lo(C)]
    int nvalid, int padm)
{
    constexpr int NV4 = C / 128;       // float4 chunks per lane (1 or 2)
    const int slot = threadIdx.x >> 5;  // 0..7
    const int l = threadIdx.x & 31;
    const int node = blockIdx.x * 8 + slot;
    if (node >= padm) return;

    float acc[4 * NV4];
#pragma unroll
    for (int v = 0; v < 4 * NV4; ++v) acc[v] = 0.f;

    if (node < nvalid) {
        float di = dinv[node];
        float w0 = di * di;
        const float* xn = x + (size_t)node * C + l * 4;
#pragma unroll
        for (int v = 0; v < NV4; ++v) {
            float4 q = *(const float4*)(xn + v * 128);
            acc[4 * v + 0] = w0 * q.x; acc[4 * v + 1] = w0 * q.y;
            acc[4 * v + 2] = w0 * q.z; acc[4 * v + 3] = w0 * q.w;
        }

        int j0 = offs[node], j1 = offs[node + 1];
        int j = j0;
        for (; j + 4 <= j1; j += 4) {
            int s0 = csr_src[j],     s1 = csr_src[j + 1];
            int s2 = csr_src[j + 2], s3 = csr_src[j + 3];
            float w0e = csr_w[j],     w1e = csr_w[j + 1];
            float w2e = csr_w[j + 2], w3e = csr_w[j + 3];
            const float* r0 = x + (size_t)s0 * C + l * 4;
            const float* r1 = x + (size_t)s1 * C + l * 4;
            const float* r2 = x + (size_t)s2 * C + l * 4;
            const float* r3 = x + (size_t)s3 * C + l * 4;
#pragma unroll
            for (int v = 0; v < NV4; ++v) {
                float4 q0 = *(const float4*)(r0 + v * 128);
                float4 q1 = *(const float4*)(r1 + v * 128);
                float4 q2 = *(const float4*)(r2 + v * 128);
                float4 q3 = *(const float4*)(r3 + v * 128);
                acc[4*v+0] = fmaf(w0e, q0.x, acc[4*v+0]); acc[4*v+1] = fmaf(w0e, q0.y, acc[4*v+1]);
                acc[4*v+2] = fmaf(w0e, q0.z, acc[4*v+2]); acc[4*v+3] = fmaf(w0e, q0.w, acc[4*v+3]);
                acc[4*v+0] = fmaf(w1e, q1.x, acc[4*v+0]); acc[4*v+1] = fmaf(w1e, q1.y, acc[4*v+1]);
                acc[4*v+2] = fmaf(w1e, q1.z, acc[4*v+2]); acc[4*v+3] = fmaf(w1e, q1.w, acc[4*v+3]);
                acc[4*v+0] = fmaf(w2e, q2.x, acc[4*v+0]); acc[4*v+1] = fmaf(w2e, q2.y, acc[4*v+1]);
                acc[4*v+2] = fmaf(w2e, q2.z, acc[4*v+2]); acc[4*v+3] = fmaf(w2e, q2.w, acc[4*v+3]);
                acc[4*v+0] = fmaf(w3e, q3.x, acc[4*v+0]); acc[4*v+1] = fmaf(w3e, q3.y, acc[4*v+1]);
                acc[4*v+2] = fmaf(w3e, q3.z, acc[4*v+2]); acc[4*v+3] = fmaf(w3e, q3.w, acc[4*v+3]);
            }
        }
        for (; j < j1; ++j) {
            int s0 = csr_src[j];
            float w0e = csr_w[j];
            const float* r0 = x + (size_t)s0 * C + l * 4;
#pragma unroll
            for (int v = 0; v < NV4; ++v) {
                float4 q0 = *(const float4*)(r0 + v * 128);
                acc[4*v+0] = fmaf(w0e, q0.x, acc[4*v+0]); acc[4*v+1] = fmaf(w0e, q0.y, acc[4*v+1]);
                acc[4*v+2] = fmaf(w0e, q0.z, acc[4*v+2]); acc[4*v+3] = fmaf(w0e, q0.w, acc[4*v+3]);
            }
        }
    }

    u16* po = out2 + (size_t)node * (2 * C);
#pragma unroll
    for (int v = 0; v < NV4; ++v) {
        u16 hi[4], lo[4];
#pragma unroll
        for (int q = 0; q < 4; ++q) {
            float a = acc[4 * v + q];
            hi[q] = f32_bf16_rne(a);
            lo[q] = f32_bf16_rne(a - bf16_f32(hi[q]));
        }
        u64 hw = (u64)hi[0] | ((u64)hi[1] << 16) | ((u64)hi[2] << 32) | ((u64)hi[3] << 48);
        u64 lw = (u64)lo[0] | ((u64)lo[1] << 16) | ((u64)lo[2] << 32) | ((u64)lo[3] << 48);
        int col = l * 4 + v * 128;
        *(u64*)(po + col) = hw;
        *(u64*)(po + C + col) = lw;
    }
}

// ---------------- 128-tile MFMA GEMM (layers 1-3) ----------------

template <int EPI>
__global__ __launch_bounds__(256, 4) void k_mfma_gemm(
    const u16* __restrict__ A2,
    const u16* __restrict__ W2,
    const float* __restrict__ bias,
    float* __restrict__ Cf,
    u16* __restrict__ Cs,
    int N, int K, int Mvalid, int nby)
{
    __shared__ u16 At[128 * 64];
    __shared__ u16 Bt[128 * 64];

    const int nwg = gridDim.x;
    const int orig = blockIdx.x;
    const int q8 = nwg >> 3, r8 = nwg & 7;
    const int xcd = orig & 7, slot = orig >> 3;
    const int L = (xcd < r8 ? xcd * (q8 + 1) : r8 * (q8 + 1) + (xcd - r8) * q8) + slot;
    const int by = L % nby;
    const int bx = L / nby;
    const int bm0 = bx * 128;
    const int bn0 = by * 128;
    const int tid = threadIdx.x;
    const int lane = tid & 63;
    const int w = tid >> 6, wr = w >> 1, wc = w & 1;
    const int g = lane >> 4, rl = lane & 15;
    const int K2 = 2 * K;

    f32x4 acc[4][4];
#pragma unroll
    for (int i = 0; i < 4; ++i)
#pragma unroll
        for (int j = 0; j < 4; ++j) {
            acc[i][j][0] = 0.f; acc[i][j][1] = 0.f; acc[i][j][2] = 0.f; acc[i][j][3] = 0.f;
        }

    size_t aoff[4], boff[4];
    int ldsb[4];
#pragma unroll
    for (int r = 0; r < 4; ++r) {
        int a = r * 4096 + tid * 16;
        int row = a >> 7;
        int c = a & 127;
        int cs = c ^ ((row & 7) << 4);
        int ce = (cs < 64) ? (cs >> 1) : (K + ((cs - 64) >> 1));
        aoff[r] = (size_t)(bm0 + row) * K2 + ce;
        boff[r] = (size_t)(bn0 + row) * K2 + ce;
        ldsb[r] = a;
    }

    for (int k0 = 0; k0 < K; k0 += 32) {
#pragma unroll
        for (int r = 0; r < 4; ++r) {
            __builtin_amdgcn_global_load_lds(
                (const GAS void*)(A2 + aoff[r] + k0),
                (LAS void*)((char*)At + ldsb[r]), 16, 0, 0);
            __builtin_amdgcn_global_load_lds(
                (const GAS void*)(W2 + boff[r] + k0),
                (LAS void*)((char*)Bt + ldsb[r]), 16, 0, 0);
        }
        __syncthreads();

        bf16x8 ah[4], al[4];
#pragma unroll
        for (int m = 0; m < 4; ++m) {
            int row = wr * 64 + m * 16 + rl;
            int sw = (row & 7) << 4;
            const char* base = (const char*)At + row * 128;
            ah[m] = *(const bf16x8*)(base + ((g * 16) ^ sw));
            al[m] = *(const bf16x8*)(base + ((64 + g * 16) ^ sw));
        }
#pragma unroll
        for (int n = 0; n < 4; ++n) {
            int row = wc * 64 + n * 16 + rl;
            int sw = (row & 7) << 4;
            const char* base = (const char*)Bt + row * 128;
            bf16x8 bh = *(const bf16x8*)(base + ((g * 16) ^ sw));
            bf16x8 bl = *(const bf16x8*)(base + ((64 + g * 16) ^ sw));
#pragma unroll
            for (int m = 0; m < 4; ++m) {
                acc[m][n] = __builtin_amdgcn_mfma_f32_16x16x32_bf16(ah[m], bh, acc[m][n], 0, 0, 0);
                acc[m][n] = __builtin_amdgcn_mfma_f32_16x16x32_bf16(al[m], bh, acc[m][n], 0, 0, 0);
                acc[m][n] = __builtin_amdgcn_mfma_f32_16x16x32_bf16(ah[m], bl, acc[m][n], 0, 0, 0);
            }
        }
        __syncthreads();
    }

#pragma unroll
    for (int n = 0; n < 4; ++n) {
        int col = bn0 + wc * 64 + n * 16 + rl;
        float bv = bias[col];
#pragma unroll
        for (int m = 0; m < 4; ++m) {
            int row0 = bm0 + wr * 64 + m * 16 + g * 4;
#pragma unroll
            for (int q = 0; q < 4; ++q) {
                int row = row0 + q;
                float v = acc[m][n][q] + bv;
                if (EPI == 0) {
                    Cf[(size_t)row * N + col] = fmaxf(v, 0.f);
                } else if (EPI == 1) {
                    float rv = fmaxf(v, 0.f);
                    u16 hi = f32_bf16_rne(rv);
                    u16 lo = f32_bf16_rne(rv - bf16_f32(hi));
                    Cs[(size_t)row * (2 * N) + col] = hi;
                    Cs[(size_t)row * (2 * N) + N + col] = lo;
                } else {
                    if (row < Mvalid) Cf[(size_t)row * N + col] = v;
                }
            }
        }
    }
}

// ---------------- 256-tile 8-phase MFMA GEMM v2 (FC only) ----------------
// Counted-vmcnt schedule, FIFO-derived:
//   issues: H2(t+1)@P1(t), H0(t+2)@P2(t), H3(t+2)@P3(t), H1(t+2)@P4(t)
//   waits:  vmcnt(10)@P2 (guards H2(t) for P3), vmcnt(8)@P4 (guards H0/H1(t+1) for P1)
// Every half has >=4 phases of flight; no drain-to-0 in the main loop.
// H0=A-half0(s0,s1) H1=B-half0(s2,s3) H2=A-half1(s4,s5) H3=B-half1(s6,s7)

#define ISSUE8(s, wbuf, offA, offB)                                              \
    __builtin_amdgcn_global_load_lds(                                            \
        (const GAS void*)(((((s) >> 1) & 1) ? W2 : A2) + gb[s] +                 \
                          ((((s) >> 1) & 1) ? (offB) : (offA))),                 \
        (LAS void*)(smem + (wbuf) * 65536 + lds8[s]), 16, 0, 0)

#define RD_A8(dst, m, rbuf) do {                                                 \
    const char* _b = smem + (rbuf) * 65536 + (((m) * 2 + wr) * 16 + rl) * 128;   \
    dst[0] = *(const bf16x8*)(_b + colb0);                                       \
    dst[1] = *(const bf16x8*)(_b + colb1); } while (0)

#define RD_B8(dst, n, rbuf) do {                                                 \
    const char* _b = smem + (rbuf) * 65536 + 32768 +                             \
                     (((n) * 4 + wc) * 16 + rl) * 128;                           \
    dst[0] = *(const bf16x8*)(_b + colb0);                                       \
    dst[1] = *(const bf16x8*)(_b + colb1); } while (0)

#define MM8(qm, qn, AF, BF)                                                      \
    _Pragma("unroll") for (int ks = 0; ks < 2; ++ks)                             \
    _Pragma("unroll") for (int mm = 0; mm < 4; ++mm)                             \
    _Pragma("unroll") for (int nn = 0; nn < 2; ++nn)                             \
        acc[(qm) * 4 + mm][(qn) * 2 + nn] = __builtin_amdgcn_mfma_f32_16x16x32_bf16( \
            AF[mm][ks], BF[nn][ks], acc[(qm) * 4 + mm][(qn) * 2 + nn], 0, 0, 0);

template <int EPI>
__global__ __launch_bounds__(512, 1) void k_gemm8(
    const u16* __restrict__ A2,
    const u16* __restrict__ W2,
    const float* __restrict__ bias,
    float* __restrict__ Cf,
    u16* __restrict__ Cs,
    int N, int K, int Mvalid, int nbn)
{
    extern __shared__ char smem[];   // 131072 B

    const int nwg = gridDim.x;
    const int orig = blockIdx.x;
    const int q8 = nwg >> 3, r8 = nwg & 7;
    const int xcd = orig & 7, slot = orig >> 3;
    const int L = (xcd < r8 ? xcd * (q8 + 1) : r8 * (q8 + 1) + (xcd - r8) * q8) + slot;
    const int by = L % nbn;
    const int bx = L / nbn;
    const int bm0 = bx * 256, bn0 = by * 256;

    const int tid = threadIdx.x;
    const int lane = tid & 63;
    const int w = tid >> 6;
    const int wr = w >> 2;           // 0..1
    const int wc = w & 3;            // 0..3
    const int g = lane >> 4, rl = lane & 15;
    const int K2 = 2 * K;
    const int NT = (3 * K) >> 6;

    const int swz = (rl & 7) << 4;
    const int colb0 = (g * 16) ^ swz;
    const int colb1 = (64 + g * 16) ^ swz;

    size_t gb[8]; int lds8[8];
#pragma unroll
    for (int s = 0; s < 8; ++s) {
        int ht = s >> 1, g2 = s & 1;
        int opB = ht & 1, half = ht >> 1;
        int local = half * 16384 + g2 * 8192 + tid * 16;
        int row = local >> 7;
        int c = local & 127;
        int ce = (c ^ ((row & 7) << 4)) >> 1;
        lds8[s] = opB * 32768 + local;
        gb[s] = (size_t)((opB ? bn0 : bm0) + row) * K2 + ce;
    }

    f32x4 acc[8][4];
#pragma unroll
    for (int i = 0; i < 8; ++i)
#pragma unroll
        for (int j = 0; j < 4; ++j) {
            acc[i][j][0] = 0.f; acc[i][j][1] = 0.f; acc[i][j][2] = 0.f; acc[i][j][3] = 0.f;
        }

    auto segoffs = [&](int tt, int& oA, int& oB) {
        int ksub = tt << 6;
        int seg = (ksub >= K ? 1 : 0) + (ksub >= K2 ? 1 : 0);
        int tcol = ksub - seg * K;
        oA = (seg == 1 ? K : 0) + tcol;
        oB = (seg == 2 ? K : 0) + tcol;
    };

    // prologue (issue order matches steady-state FIFO):
    // H0(0),H3(0),H1(0),H2(0) -> buf0 ; H0(1),H3(1),H1(1) -> buf1
    {
        int oA0, oB0; segoffs(0, oA0, oB0);
        ISSUE8(0, 0, oA0, oB0); ISSUE8(1, 0, oA0, oB0);   // H0(0)
        ISSUE8(6, 0, oA0, oB0); ISSUE8(7, 0, oA0, oB0);   // H3(0)
        ISSUE8(2, 0, oA0, oB0); ISSUE8(3, 0, oA0, oB0);   // H1(0)
        ISSUE8(4, 0, oA0, oB0); ISSUE8(5, 0, oA0, oB0);   // H2(0)
        if (NT > 1) {
            int oA1, oB1; segoffs(1, oA1, oB1);
            ISSUE8(0, 1, oA1, oB1); ISSUE8(1, 1, oA1, oB1);   // H0(1)
            ISSUE8(6, 1, oA1, oB1); ISSUE8(7, 1, oA1, oB1);   // H3(1)
            ISSUE8(2, 1, oA1, oB1); ISSUE8(3, 1, oA1, oB1);   // H1(1)
            asm volatile("s_waitcnt vmcnt(8)" ::: "memory");  // H0,H3,H1(0) landed
        } else {
            asm volatile("s_waitcnt vmcnt(0)" ::: "memory");
        }
        __builtin_amdgcn_sched_barrier(0);
    }
    barx();

    bf16x8 a0[4][2], a1[4][2], b0[2][2], b1[2][2];

    for (int t = 0; t < NT; ++t) {
        const int rb = t & 1, wb = rb ^ 1;
        const bool m1 = (t + 1) < NT;
        const bool m2 = (t + 2) < NT;
        int oA1 = 0, oB1 = 0, oA2 = 0, oB2 = 0;
        if (m1) segoffs(t + 1, oA1, oB1);
        if (m2) segoffs(t + 2, oA2, oB2);

        // ---- P1: MFMA quad(0,0); reads H0(t),H1(t); issue H2(t+1) ----
        RD_A8(a0[0], 0, rb); RD_A8(a0[1], 1, rb); RD_A8(a0[2], 2, rb); RD_A8(a0[3], 3, rb);
        RD_B8(b0[0], 0, rb); RD_B8(b0[1], 1, rb);
        if (m1) { ISSUE8(4, wb, oA1, oB1); ISSUE8(5, wb, oA1, oB1); }
        barx();
        __builtin_amdgcn_s_setprio(1);
        MM8(0, 0, a0, b0);
        __builtin_amdgcn_s_setprio(0);
        barx();

        // ---- P2: MFMA quad(0,1); reads H3(t); issue H0(t+2); wait guards H2(t) ----
        RD_B8(b1[0], 2, rb); RD_B8(b1[1], 3, rb);
        if (m2) { ISSUE8(0, rb, oA2, oB2); ISSUE8(1, rb, oA2, oB2); }
        if (m2)      { asm volatile("s_waitcnt vmcnt(10)" ::: "memory"); }
        else if (m1) { asm volatile("s_waitcnt vmcnt(8)"  ::: "memory"); }
        else         { asm volatile("s_waitcnt vmcnt(0)"  ::: "memory"); }
        __builtin_amdgcn_sched_barrier(0);
        barx();
        __builtin_amdgcn_s_setprio(1);
        MM8(0, 1, a0, b1);
        __builtin_amdgcn_s_setprio(0);
        barx();

        // ---- P3: MFMA quad(1,0); reads H2(t); issue H3(t+2) ----
        RD_A8(a1[0], 4, rb); RD_A8(a1[1], 5, rb); RD_A8(a1[2], 6, rb); RD_A8(a1[3], 7, rb);
        if (m2) { ISSUE8(6, rb, oA2, oB2); ISSUE8(7, rb, oA2, oB2); }
        barx();
        __builtin_amdgcn_s_setprio(1);
        MM8(1, 0, a1, b0);
        __builtin_amdgcn_s_setprio(0);
        barx();

        // ---- P4: MFMA quad(1,1); issue H1(t+2); wait guards H0,H1(t+1) ----
        if (m2) { ISSUE8(2, rb, oA2, oB2); ISSUE8(3, rb, oA2, oB2); }
        if (m2)      { asm volatile("s_waitcnt vmcnt(8)" ::: "memory"); }
        else if (m1) { asm volatile("s_waitcnt vmcnt(2)" ::: "memory"); }
        __builtin_amdgcn_sched_barrier(0);
        barx();
        __builtin_amdgcn_s_setprio(1);
        MM8(1, 1, a1, b1);
        __builtin_amdgcn_s_setprio(0);
        barx();
    }

    // epilogue: frag (m,n) covers C rows (m*2+wr)*16.., cols (n*4+wc)*16..
#pragma unroll
    for (int n = 0; n < 4; ++n) {
        int col = bn0 + (n * 4 + wc) * 16 + rl;
        float bv = bias[col];
#pragma unroll
        for (int m = 0; m < 8; ++m) {
            int row0 = bm0 + (m * 2 + wr) * 16 + g * 4;
#pragma unroll
            for (int q = 0; q < 4; ++q) {
                int row = row0 + q;
                float v = acc[m][n][q] + bv;
                if (EPI == 0) {
                    Cf[(size_t)row * N + col] = fmaxf(v, 0.f);
                } else if (EPI == 1) {
                    float rv = fmaxf(v, 0.f);
                    u16 hi = f32_bf16_rne(rv);
                    u16 lo = f32_bf16_rne(rv - bf16_f32(hi));
                    Cs[(size_t)row * (2 * N) + col] = hi;
                    Cs[(size_t)row * (2 * N) + N + col] = lo;
                } else {
                    if (row < Mvalid) Cf[(size_t)row * N + col] = v;
                }
            }
        }
    }
}

// ---------------- launch ----------------

static inline size_t align_up(size_t x, size_t a) { return (x + a - 1) & ~(a - 1); }

extern "C" void kernel_launch(void* const* d_in, const int* in_sizes, int n_in,
                              void* d_out, int out_size, void* d_ws, size_t ws_size,
                              hipStream_t stream) {
    const int*   edge_index = (const int*)d_in[0];
    const float* node = (const float*)d_in[1];
    const float* W1 = (const float*)d_in[2];
    const float* b1 = (const float*)d_in[3];
    const float* W2 = (const float*)d_in[4];
    const float* b2 = (const float*)d_in[5];
    const float* W3 = (const float*)d_in[6];
    const float* b3 = (const float*)d_in[7];
    const float* Wfc = (const float*)d_in[8];
    const float* bfc = (const float*)d_in[9];
    float* out = (float*)d_out;

    const int E = in_sizes[0] / 2;   // 400000
    const int NV = NNODES;
    const int P = PADM;

    (void)hipFuncSetAttribute((const void*)k_gemm8<2>, hipFuncAttributeMaxDynamicSharedMemorySize, 131072);

    // workspace layout
    char* ws = (char*)d_ws;
    size_t off = 0;
    int* cnt = (int*)(ws + off);          off = align_up(off + (size_t)NV * 4, 1024);
    int* offs = (int*)(ws + off);         off = align_up(off + (size_t)(NV + 1) * 4, 1024);
    int* cursor = (int*)(ws + off);       off = align_up(off + (size_t)NV * 4, 1024);
    float* dinv = (float*)(ws + off);     off = align_up(off + (size_t)NV * 4, 1024);
    int* csr_src = (int*)(ws + off);      off = align_up(off + (size_t)E * 4, 1024);
    float* csr_w = (float*)(ws + off);    off = align_up(off + (size_t)E * 4, 1024);
    u16* W1s = (u16*)(ws + off);          off = align_up(off + (size_t)128 * 256 * 2, 1024);
    u16* W2s = (u16*)(ws + off);          off = align_up(off + (size_t)256 * 256 * 2, 1024);
    u16* W3s = (u16*)(ws + off);          off = align_up(off + (size_t)512 * 512 * 2, 1024);
    u16* Wfcs = (u16*)(ws + off);         off = align_up(off + (size_t)1024 * 1024 * 2, 1024);
    u16* A1s = (u16*)(ws + off);          off = align_up(off + (size_t)P * 256 * 2, 1024);
    u16* A3s = (u16*)(ws + off);          off = align_up(off + (size_t)P * 512 * 2, 1024);
    u16* A4s = (u16*)(ws + off);          off = align_up(off + (size_t)P * 1024 * 2, 1024);
    float* xbuf1 = (float*)(ws + off);    off = align_up(off + (size_t)P * 128 * 4, 1024);
    float* xbuf2 = (float*)(ws + off);    off = align_up(off + (size_t)P * 256 * 4, 1024);

    const int* src = edge_index;
    const int* dst = edge_index + E;

    // weight splits
    k_splitW<<<(128 * 128 + 255) / 256, 256, 0, stream>>>(W1, W1s, 128 * 128, 128);
    k_splitW<<<(256 * 128 + 255) / 256, 256, 0, stream>>>(W2, W2s, 256 * 128, 128);
    k_splitW<<<(512 * 256 + 255) / 256, 256, 0, stream>>>(W3, W3s, 512 * 256, 256);
    k_splitW<<<(1024 * 512 + 255) / 256, 256, 0, stream>>>(Wfc, Wfcs, 1024 * 512, 512);

    // CSR build
    k_zero_cnt<<<(NV + 255) / 256, 256, 0, stream>>>(cnt, NV);
    k_count<<<(E + 255) / 256, 256, 0, stream>>>(dst, E, cnt);
    k_dinv<<<(NV + 255) / 256, 256, 0, stream>>>(cnt, dinv, NV);
    k_scan<<<1, 1024, 0, stream>>>(cnt, NV, offs, cursor);
    k_fill<<<(E + 255) / 256, 256, 0, stream>>>(src, dst, E, cursor, dinv, csr_src, csr_w);

    dim3 blk(256);
    const int aggGrid = P / 8;   // 6272
    const int nbx = P / 128;     // 392
    const int nbm8 = P / 256;    // 196

    // layer 1: agg -> A1s, 128-tile gemm -> xbuf1
    k_aggregate_split<128><<<aggGrid, blk, 0, stream>>>(node, offs, csr_src, csr_w, dinv, A1s, NV, P);
    k_mfma_gemm<0><<<nbx * 1, blk, 0, stream>>>(A1s, W1s, b1, xbuf1, nullptr, 128, 128, P, 1);

    // layer 2: agg -> A1s, 128-tile gemm -> xbuf2
    k_aggregate_split<128><<<aggGrid, blk, 0, stream>>>(xbuf1, offs, csr_src, csr_w, dinv, A1s, NV, P);
    k_mfma_gemm<0><<<nbx * 2, blk, 0, stream>>>(A1s, W2s, b2, xbuf2, nullptr, 256, 128, P, 2);

    // layer 3: agg -> A3s, 128-tile gemm (split-bf16 out) -> A4s
    k_aggregate_split<256><<<aggGrid, blk, 0, stream>>>(xbuf2, offs, csr_src, csr_w, dinv, A3s, NV, P);
    k_mfma_gemm<1><<<nbx * 4, blk, 0, stream>>>(A3s, W3s, b3, nullptr, A4s, 512, 256, P, 4);

    // FC: 8-phase v2 (N=1024, K=512, NT=24) -> out (f32, rows < NV)
    k_gemm8<2><<<nbm8 * 4, 512, 131072, stream>>>(A4s, Wfcs, bfc, out, nullptr, 1024, 512, NV, 4);
}

// Round 6
// 585.816 us; speedup vs baseline: 1.0933x; 1.0933x over previous
//
#include <hip/hip_runtime.h>
#include <hip/hip_bf16.h>

typedef unsigned short u16;
typedef unsigned int   u32;
typedef unsigned long long u64;
typedef __attribute__((ext_vector_type(8))) short bf16x8;
typedef __attribute__((ext_vector_type(8))) short s16x8;
typedef __attribute__((ext_vector_type(4))) float f32x4;

#define NNODES 50000
#define PADM   50176          // 256 * 196, multiple of 128 and 16

#define GAS __attribute__((address_space(1)))
#define LAS __attribute__((address_space(3)))

__device__ __forceinline__ u16 f32_bf16_rne(float x) {
    u32 u = __float_as_uint(x);
    return (u16)((u + 0x7fffu + ((u >> 16) & 1u)) >> 16);
}
__device__ __forceinline__ float bf16_f32(u16 h) {
    return __uint_as_float(((u32)h) << 16);
}

// ---------------- CSR build ----------------

__global__ void k_zero_cnt(int* __restrict__ cnt, int n) {
    int i = blockIdx.x * 256 + threadIdx.x;
    if (i < n) cnt[i] = 0;
}

__global__ void k_count(const int* __restrict__ dst, int E, int* __restrict__ cnt) {
    int e = blockIdx.x * 256 + threadIdx.x;
    if (e < E) atomicAdd(&cnt[dst[e]], 1);
}

__global__ void k_dinv(const int* __restrict__ cnt, float* __restrict__ dinv, int n) {
    int i = blockIdx.x * 256 + threadIdx.x;
    if (i < n) dinv[i] = rsqrtf((float)(cnt[i] + 1));   // +1 self loop
}

__global__ __launch_bounds__(1024) void k_scan(const int* __restrict__ cnt, int n,
                                               int* __restrict__ offs, int* __restrict__ cursor) {
    __shared__ int sums[1024];
    int t = threadIdx.x;
    int per = (n + 1023) / 1024;
    int start = t * per;
    int end = start + per; if (end > n) end = n;
    int s = 0;
    for (int i = start; i < end; ++i) s += cnt[i];
    sums[t] = s;
    __syncthreads();
    for (int d = 1; d < 1024; d <<= 1) {
        int v = (t >= d) ? sums[t - d] : 0;
        __syncthreads();
        sums[t] += v;
        __syncthreads();
    }
    int base = (t == 0) ? 0 : sums[t - 1];
    for (int i = start; i < end; ++i) {
        offs[i] = base; cursor[i] = base;
        base += cnt[i];
    }
    if (t == 1023) offs[n] = sums[1023];
}

__global__ void k_fill(const int* __restrict__ src, const int* __restrict__ dst, int E,
                       int* __restrict__ cursor, const float* __restrict__ dinv,
                       int* __restrict__ csr_src, float* __restrict__ csr_w) {
    int e = blockIdx.x * 256 + threadIdx.x;
    if (e < E) {
        int s = src[e], d = dst[e];
        int slot = atomicAdd(&cursor[d], 1);
        csr_src[slot] = s;
        csr_w[slot] = dinv[s] * dinv[d];
    }
}

// ---------------- weight split: W[N][K] f32 -> [N][2K] bf16 [hi|lo] ----------------

__global__ void k_splitW(const float* __restrict__ W, u16* __restrict__ W2, int total, int K) {
    int i = blockIdx.x * 256 + threadIdx.x;
    if (i >= total) return;
    int n = i / K, k = i - n * K;
    float w = W[i];
    u16 hi = f32_bf16_rne(w);
    u16 lo = f32_bf16_rne(w - bf16_f32(hi));
    W2[(size_t)n * (2 * K) + k] = hi;
    W2[(size_t)n * (2 * K) + K + k] = lo;
}

// ---------------- per-row i16 quantization: x[row][C] f32 -> q i16 + ds scale ----------------
// q = round(x * 32767/rowmax);  dequant x ~= q * ds,  ds = rowmax/32767.
// |err| <= rowmax * 1.53e-5  (negligible vs bf16-split path budget)

template <int C>   // 128 or 256
__global__ __launch_bounds__(256) void k_rowquant(
    const float* __restrict__ x, short* __restrict__ qo, float* __restrict__ ds, int nrows)
{
    constexpr int V = C / 64;
    const int wave = threadIdx.x >> 6, lane = threadIdx.x & 63;
    const int row = blockIdx.x * 4 + wave;
    if (row >= nrows) return;
    const float* xr = x + (size_t)row * C + lane * V;
    float v[V];
    if (V == 2) { float2 t = *(const float2*)xr; v[0] = t.x; v[1] = t.y; }
    else        { float4 t = *(const float4*)xr; v[0] = t.x; v[1] = t.y; v[2] = t.z; v[3] = t.w; }
    float m = 0.f;
#pragma unroll
    for (int i = 0; i < V; ++i) m = fmaxf(m, fabsf(v[i]));
#pragma unroll
    for (int d = 32; d >= 1; d >>= 1) m = fmaxf(m, __shfl_xor(m, d));
    float inv = (m > 0.f) ? 32767.f / m : 0.f;
    if (lane == 0) ds[row] = (m > 0.f) ? m * (1.f / 32767.f) : 0.f;
    short* qr = qo + (size_t)row * C + lane * V;
    if (V == 2) {
        u32 wd = (u32)(u16)(short)__float2int_rn(v[0] * inv)
               | ((u32)(u16)(short)__float2int_rn(v[1] * inv) << 16);
        *(u32*)qr = wd;
    } else {
        u64 wd = 0;
#pragma unroll
        for (int i = 0; i < 4; ++i)
            wd |= (u64)(u16)(short)__float2int_rn(v[i] * inv) << (16 * i);
        *(u64*)qr = wd;
    }
}

// ---------------- aggregation over i16 rows (16 lanes/node) + split-bf16 output ----------------

template <int C>   // 128 or 256
__global__ __launch_bounds__(256) void k_agg_q(
    const short* __restrict__ q, const float* __restrict__ ds,
    const int* __restrict__ offs, const int* __restrict__ csr_src,
    const float* __restrict__ csr_w, const float* __restrict__ dinv,
    u16* __restrict__ out2,        // [PADM][2C] bf16 [hi(C)|lo(C)], pad rows zeroed
    int nvalid, int padm)
{
    constexpr int NS = C / 128;     // short8 chunks per lane (1 or 2)
    const int sub = threadIdx.x >> 4;   // 0..15
    const int l = threadIdx.x & 15;
    const int node = blockIdx.x * 16 + sub;
    if (node >= padm) return;

    float acc[8 * NS];
#pragma unroll
    for (int i = 0; i < 8 * NS; ++i) acc[i] = 0.f;

    if (node < nvalid) {
        float di = dinv[node];
        float c0 = di * di * ds[node];
        const short* qn = q + (size_t)node * C + l * 8;
#pragma unroll
        for (int k = 0; k < NS; ++k) {
            s16x8 h = *(const s16x8*)(qn + k * 128);
#pragma unroll
            for (int i = 0; i < 8; ++i) acc[k * 8 + i] = c0 * (float)h[i];
        }

        int j0 = offs[node], j1 = offs[node + 1];
        int j = j0;
        for (; j + 4 <= j1; j += 4) {
            int s0 = csr_src[j],     s1 = csr_src[j + 1];
            int s2 = csr_src[j + 2], s3 = csr_src[j + 3];
            float c0e = csr_w[j]     * ds[s0];
            float c1e = csr_w[j + 1] * ds[s1];
            float c2e = csr_w[j + 2] * ds[s2];
            float c3e = csr_w[j + 3] * ds[s3];
            const short* r0 = q + (size_t)s0 * C + l * 8;
            const short* r1 = q + (size_t)s1 * C + l * 8;
            const short* r2 = q + (size_t)s2 * C + l * 8;
            const short* r3 = q + (size_t)s3 * C + l * 8;
#pragma unroll
            for (int k = 0; k < NS; ++k) {
                s16x8 h0 = *(const s16x8*)(r0 + k * 128);
                s16x8 h1 = *(const s16x8*)(r1 + k * 128);
                s16x8 h2 = *(const s16x8*)(r2 + k * 128);
                s16x8 h3 = *(const s16x8*)(r3 + k * 128);
#pragma unroll
                for (int i = 0; i < 8; ++i) {
                    acc[k * 8 + i] = fmaf(c0e, (float)h0[i], acc[k * 8 + i]);
                    acc[k * 8 + i] = fmaf(c1e, (float)h1[i], acc[k * 8 + i]);
                    acc[k * 8 + i] = fmaf(c2e, (float)h2[i], acc[k * 8 + i]);
                    acc[k * 8 + i] = fmaf(c3e, (float)h3[i], acc[k * 8 + i]);
                }
            }
        }
        for (; j < j1; ++j) {
            int s0 = csr_src[j];
            float c0e = csr_w[j] * ds[s0];
            const short* r0 = q + (size_t)s0 * C + l * 8;
#pragma unroll
            for (int k = 0; k < NS; ++k) {
                s16x8 h0 = *(const s16x8*)(r0 + k * 128);
#pragma unroll
                for (int i = 0; i < 8; ++i)
                    acc[k * 8 + i] = fmaf(c0e, (float)h0[i], acc[k * 8 + i]);
            }
        }
    }

    u16* po = out2 + (size_t)node * (2 * C);
#pragma unroll
    for (int k = 0; k < NS; ++k) {
        int col = l * 8 + k * 128;
        u64 hw0 = 0, hw1 = 0, lw0 = 0, lw1 = 0;
#pragma unroll
        for (int i = 0; i < 4; ++i) {
            float a = acc[k * 8 + i];
            u16 h = f32_bf16_rne(a); u16 lo = f32_bf16_rne(a - bf16_f32(h));
            hw0 |= (u64)h << (16 * i); lw0 |= (u64)lo << (16 * i);
        }
#pragma unroll
        for (int i = 0; i < 4; ++i) {
            float a = acc[k * 8 + 4 + i];
            u16 h = f32_bf16_rne(a); u16 lo = f32_bf16_rne(a - bf16_f32(h));
            hw1 |= (u64)h << (16 * i); lw1 |= (u64)lo << (16 * i);
        }
        *(u64*)(po + col) = hw0;       *(u64*)(po + col + 4) = hw1;
        *(u64*)(po + C + col) = lw0;   *(u64*)(po + C + col + 4) = lw1;
    }
}

// ---------------- 128-tile MFMA GEMM over split-bf16 (all layers + FC) ----------------

template <int EPI>
__global__ __launch_bounds__(256, 4) void k_mfma_gemm(
    const u16* __restrict__ A2,
    const u16* __restrict__ W2,
    const float* __restrict__ bias,
    float* __restrict__ Cf,
    u16* __restrict__ Cs,
    int N, int K, int Mvalid, int nby)
{
    __shared__ u16 At[128 * 64];
    __shared__ u16 Bt[128 * 64];

    const int nwg = gridDim.x;
    const int orig = blockIdx.x;
    const int q8 = nwg >> 3, r8 = nwg & 7;
    const int xcd = orig & 7, slot = orig >> 3;
    const int L = (xcd < r8 ? xcd * (q8 + 1) : r8 * (q8 + 1) + (xcd - r8) * q8) + slot;
    const int by = L % nby;
    const int bx = L / nby;
    const int bm0 = bx * 128;
    const int bn0 = by * 128;
    const int tid = threadIdx.x;
    const int lane = tid & 63;
    const int w = tid >> 6, wr = w >> 1, wc = w & 1;
    const int g = lane >> 4, rl = lane & 15;
    const int K2 = 2 * K;

    f32x4 acc[4][4];
#pragma unroll
    for (int i = 0; i < 4; ++i)
#pragma unroll
        for (int j = 0; j < 4; ++j) {
            acc[i][j][0] = 0.f; acc[i][j][1] = 0.f; acc[i][j][2] = 0.f; acc[i][j][3] = 0.f;
        }

    size_t aoff[4], boff[4];
    int ldsb[4];
#pragma unroll
    for (int r = 0; r < 4; ++r) {
        int a = r * 4096 + tid * 16;
        int row = a >> 7;
        int c = a & 127;
        int cs = c ^ ((row & 7) << 4);
        int ce = (cs < 64) ? (cs >> 1) : (K + ((cs - 64) >> 1));
        aoff[r] = (size_t)(bm0 + row) * K2 + ce;
        boff[r] = (size_t)(bn0 + row) * K2 + ce;
        ldsb[r] = a;
    }

    for (int k0 = 0; k0 < K; k0 += 32) {
#pragma unroll
        for (int r = 0; r < 4; ++r) {
            __builtin_amdgcn_global_load_lds(
                (const GAS void*)(A2 + aoff[r] + k0),
                (LAS void*)((char*)At + ldsb[r]), 16, 0, 0);
            __builtin_amdgcn_global_load_lds(
                (const GAS void*)(W2 + boff[r] + k0),
                (LAS void*)((char*)Bt + ldsb[r]), 16, 0, 0);
        }
        __syncthreads();

        bf16x8 ah[4], al[4];
#pragma unroll
        for (int m = 0; m < 4; ++m) {
            int row = wr * 64 + m * 16 + rl;
            int sw = (row & 7) << 4;
            const char* base = (const char*)At + row * 128;
            ah[m] = *(const bf16x8*)(base + ((g * 16) ^ sw));
            al[m] = *(const bf16x8*)(base + ((64 + g * 16) ^ sw));
        }
#pragma unroll
        for (int n = 0; n < 4; ++n) {
            int row = wc * 64 + n * 16 + rl;
            int sw = (row & 7) << 4;
            const char* base = (const char*)Bt + row * 128;
            bf16x8 bh = *(const bf16x8*)(base + ((g * 16) ^ sw));
            bf16x8 bl = *(const bf16x8*)(base + ((64 + g * 16) ^ sw));
#pragma unroll
            for (int m = 0; m < 4; ++m) {
                acc[m][n] = __builtin_amdgcn_mfma_f32_16x16x32_bf16(ah[m], bh, acc[m][n], 0, 0, 0);
                acc[m][n] = __builtin_amdgcn_mfma_f32_16x16x32_bf16(al[m], bh, acc[m][n], 0, 0, 0);
                acc[m][n] = __builtin_amdgcn_mfma_f32_16x16x32_bf16(ah[m], bl, acc[m][n], 0, 0, 0);
            }
        }
        __syncthreads();
    }

#pragma unroll
    for (int n = 0; n < 4; ++n) {
        int col = bn0 + wc * 64 + n * 16 + rl;
        float bv = bias[col];
#pragma unroll
        for (int m = 0; m < 4; ++m) {
            int row0 = bm0 + wr * 64 + m * 16 + g * 4;
#pragma unroll
            for (int q = 0; q < 4; ++q) {
                int row = row0 + q;
                float v = acc[m][n][q] + bv;
                if (EPI == 0) {
                    Cf[(size_t)row * N + col] = fmaxf(v, 0.f);
                } else if (EPI == 1) {
                    float rv = fmaxf(v, 0.f);
                    u16 hi = f32_bf16_rne(rv);
                    u16 lo = f32_bf16_rne(rv - bf16_f32(hi));
                    Cs[(size_t)row * (2 * N) + col] = hi;
                    Cs[(size_t)row * (2 * N) + N + col] = lo;
                } else {
                    if (row < Mvalid) Cf[(size_t)row * N + col] = v;
                }
            }
        }
    }
}

// ---------------- launch ----------------

static inline size_t align_up(size_t x, size_t a) { return (x + a - 1) & ~(a - 1); }

extern "C" void kernel_launch(void* const* d_in, const int* in_sizes, int n_in,
                              void* d_out, int out_size, void* d_ws, size_t ws_size,
                              hipStream_t stream) {
    const int*   edge_index = (const int*)d_in[0];
    const float* node = (const float*)d_in[1];
    const float* W1 = (const float*)d_in[2];
    const float* b1 = (const float*)d_in[3];
    const float* W2 = (const float*)d_in[4];
    const float* b2 = (const float*)d_in[5];
    const float* W3 = (const float*)d_in[6];
    const float* b3 = (const float*)d_in[7];
    const float* Wfc = (const float*)d_in[8];
    const float* bfc = (const float*)d_in[9];
    float* out = (float*)d_out;

    const int E = in_sizes[0] / 2;   // 400000
    const int NV = NNODES;
    const int P = PADM;

    // workspace layout
    char* ws = (char*)d_ws;
    size_t off = 0;
    int* cnt = (int*)(ws + off);          off = align_up(off + (size_t)NV * 4, 1024);
    int* offs = (int*)(ws + off);         off = align_up(off + (size_t)(NV + 1) * 4, 1024);
    int* cursor = (int*)(ws + off);       off = align_up(off + (size_t)NV * 4, 1024);
    float* dinv = (float*)(ws + off);     off = align_up(off + (size_t)NV * 4, 1024);
    int* csr_src = (int*)(ws + off);      off = align_up(off + (size_t)E * 4, 1024);
    float* csr_w = (float*)(ws + off);    off = align_up(off + (size_t)E * 4, 1024);
    u16* W1s = (u16*)(ws + off);          off = align_up(off + (size_t)128 * 256 * 2, 1024);
    u16* W2s = (u16*)(ws + off);          off = align_up(off + (size_t)256 * 256 * 2, 1024);
    u16* W3s = (u16*)(ws + off);          off = align_up(off + (size_t)512 * 512 * 2, 1024);
    u16* Wfcs = (u16*)(ws + off);         off = align_up(off + (size_t)1024 * 1024 * 2, 1024);
    u16* A1s = (u16*)(ws + off);          off = align_up(off + (size_t)P * 256 * 2, 1024);
    u16* A3s = (u16*)(ws + off);          off = align_up(off + (size_t)P * 512 * 2, 1024);
    u16* A4s = (u16*)(ws + off);          off = align_up(off + (size_t)P * 1024 * 2, 1024);
    float* xbuf1 = (float*)(ws + off);    off = align_up(off + (size_t)P * 128 * 4, 1024);
    float* xbuf2 = (float*)(ws + off);    off = align_up(off + (size_t)P * 256 * 4, 1024);
    short* q01 = (short*)(ws + off);      off = align_up(off + (size_t)P * 128 * 2, 1024);
    float* ds01 = (float*)(ws + off);     off = align_up(off + (size_t)P * 4, 1024);
    float* ds2 = (float*)(ws + off);      off = align_up(off + (size_t)P * 4, 1024);
    short* q2 = (short*)xbuf1;            // alias: xbuf1 dead once q2 is built

    const int* src = edge_index;
    const int* dst = edge_index + E;

    // weight splits
    k_splitW<<<(128 * 128 + 255) / 256, 256, 0, stream>>>(W1, W1s, 128 * 128, 128);
    k_splitW<<<(256 * 128 + 255) / 256, 256, 0, stream>>>(W2, W2s, 256 * 128, 128);
    k_splitW<<<(512 * 256 + 255) / 256, 256, 0, stream>>>(W3, W3s, 512 * 256, 256);
    k_splitW<<<(1024 * 512 + 255) / 256, 256, 0, stream>>>(Wfc, Wfcs, 1024 * 512, 512);

    // CSR build
    k_zero_cnt<<<(NV + 255) / 256, 256, 0, stream>>>(cnt, NV);
    k_count<<<(E + 255) / 256, 256, 0, stream>>>(dst, E, cnt);
    k_dinv<<<(NV + 255) / 256, 256, 0, stream>>>(cnt, dinv, NV);
    k_scan<<<1, 1024, 0, stream>>>(cnt, NV, offs, cursor);
    k_fill<<<(E + 255) / 256, 256, 0, stream>>>(src, dst, E, cursor, dinv, csr_src, csr_w);

    dim3 blk(256);
    const int qGrid = (NV + 3) / 4;    // rowquant: 4 rows/block
    const int aGrid = P / 16;          // agg: 16 nodes/block
    const int nbx = P / 128;           // 392

    // layer 1: quant(node) -> q01, agg -> A1s, gemm -> xbuf1
    k_rowquant<128><<<qGrid, blk, 0, stream>>>(node, q01, ds01, NV);
    k_agg_q<128><<<aGrid, blk, 0, stream>>>(q01, ds01, offs, csr_src, csr_w, dinv, A1s, NV, P);
    k_mfma_gemm<0><<<nbx * 1, blk, 0, stream>>>(A1s, W1s, b1, xbuf1, nullptr, 128, 128, P, 1);

    // layer 2: quant(xbuf1) -> q01, agg -> A1s, gemm -> xbuf2
    k_rowquant<128><<<qGrid, blk, 0, stream>>>(xbuf1, q01, ds01, NV);
    k_agg_q<128><<<aGrid, blk, 0, stream>>>(q01, ds01, offs, csr_src, csr_w, dinv, A1s, NV, P);
    k_mfma_gemm<0><<<nbx * 2, blk, 0, stream>>>(A1s, W2s, b2, xbuf2, nullptr, 256, 128, P, 2);

    // layer 3: quant(xbuf2) -> q2 (aliases xbuf1), agg -> A3s, gemm (split-bf16 out) -> A4s
    k_rowquant<256><<<qGrid, blk, 0, stream>>>(xbuf2, q2, ds2, NV);
    k_agg_q<256><<<aGrid, blk, 0, stream>>>(q2, ds2, offs, csr_src, csr_w, dinv, A3s, NV, P);
    k_mfma_gemm<1><<<nbx * 4, blk, 0, stream>>>(A3s, W3s, b3, nullptr, A4s, 512, 256, P, 4);

    // FC: proven 128-tile kernel (N=1024, K=512) -> out (f32, rows < NV)
    k_mfma_gemm<2><<<nbx * 8, blk, 0, stream>>>(A4s, Wfcs, bfc, out, nullptr, 1024, 512, NV, 8);
}

// Round 7
// 516.820 us; speedup vs baseline: 1.2393x; 1.1335x over previous
//
#include <hip/hip_runtime.h>
#include <hip/hip_bf16.h>

typedef unsigned char  u8;
typedef unsigned short u16;
typedef unsigned int   u32;
typedef unsigned long long u64;
typedef signed char i8;
typedef __attribute__((ext_vector_type(8))) short s16x8;
typedef __attribute__((ext_vector_type(4))) int   i32x4;

#define NNODES 50000
#define PADM   50176          // 256 * 196, multiple of 128 and 16

#define GAS __attribute__((address_space(1)))
#define LAS __attribute__((address_space(3)))

// ---------------- CSR build ----------------

__global__ void k_zero_cnt(int* __restrict__ cnt, int n) {
    int i = blockIdx.x * 256 + threadIdx.x;
    if (i < n) cnt[i] = 0;
}

__global__ void k_count(const int* __restrict__ dst, int E, int* __restrict__ cnt) {
    int e = blockIdx.x * 256 + threadIdx.x;
    if (e < E) atomicAdd(&cnt[dst[e]], 1);
}

__global__ void k_dinv(const int* __restrict__ cnt, float* __restrict__ dinv, int n) {
    int i = blockIdx.x * 256 + threadIdx.x;
    if (i < n) dinv[i] = rsqrtf((float)(cnt[i] + 1));   // +1 self loop
}

__global__ __launch_bounds__(1024) void k_scan(const int* __restrict__ cnt, int n,
                                               int* __restrict__ offs, int* __restrict__ cursor) {
    __shared__ int sums[1024];
    int t = threadIdx.x;
    int per = (n + 1023) / 1024;
    int start = t * per;
    int end = start + per; if (end > n) end = n;
    int s = 0;
    for (int i = start; i < end; ++i) s += cnt[i];
    sums[t] = s;
    __syncthreads();
    for (int d = 1; d < 1024; d <<= 1) {
        int v = (t >= d) ? sums[t - d] : 0;
        __syncthreads();
        sums[t] += v;
        __syncthreads();
    }
    int base = (t == 0) ? 0 : sums[t - 1];
    for (int i = start; i < end; ++i) {
        offs[i] = base; cursor[i] = base;
        base += cnt[i];
    }
    if (t == 1023) offs[n] = sums[1023];
}

__global__ void k_fill(const int* __restrict__ src, const int* __restrict__ dst, int E,
                       int* __restrict__ cursor, const float* __restrict__ dinv,
                       int* __restrict__ csr_src, float* __restrict__ csr_w) {
    int e = blockIdx.x * 256 + threadIdx.x;
    if (e < E) {
        int s = src[e], d = dst[e];
        int slot = atomicAdd(&cursor[d], 1);
        csr_src[slot] = s;
        csr_w[slot] = dinv[s] * dinv[d];
    }
}

// ---------------- per-row i8-split quantization ----------------
// x[row][K] f32 -> q = round(x*32256/rowmax) i16 -> qh=(q+128)>>8, ql=q-256*qh
// planes: qp[row][2K] i8 = [hi(K) | lo(K)]; ds[row] = rowmax/32256.
// Used for weights and for the FC input (xbuf3).

template <int K>   // 128, 256, 512
__global__ __launch_bounds__(256) void k_quant_i8(
    const float* __restrict__ x, i8* __restrict__ qp, float* __restrict__ ds, int nrows)
{
    constexpr int V = K / 64;    // 2, 4, 8
    const int wave = threadIdx.x >> 6, lane = threadIdx.x & 63;
    const int row = blockIdx.x * 4 + wave;
    if (row >= nrows) return;
    const float* xr = x + (size_t)row * K + lane * V;
    float v[V];
    if constexpr (V == 2) {
        float2 t = *(const float2*)xr; v[0] = t.x; v[1] = t.y;
    } else if constexpr (V == 4) {
        float4 t = *(const float4*)xr; v[0] = t.x; v[1] = t.y; v[2] = t.z; v[3] = t.w;
    } else {
        float4 t0 = *(const float4*)xr; float4 t1 = *(const float4*)(xr + 4);
        v[0] = t0.x; v[1] = t0.y; v[2] = t0.z; v[3] = t0.w;
        v[4] = t1.x; v[5] = t1.y; v[6] = t1.z; v[7] = t1.w;
    }
    float m = 0.f;
#pragma unroll
    for (int i = 0; i < V; ++i) m = fmaxf(m, fabsf(v[i]));
#pragma unroll
    for (int d = 32; d >= 1; d >>= 1) m = fmaxf(m, __shfl_xor(m, d));
    float inv = (m > 0.f) ? 32256.f / m : 0.f;
    if (lane == 0) ds[row] = (m > 0.f) ? m * (1.f / 32256.f) : 0.f;
    u64 hw = 0, lw = 0;
#pragma unroll
    for (int i = 0; i < V; ++i) {
        int q = __float2int_rn(v[i] * inv);
        int qh = (q + 128) >> 8;
        int ql = q - (qh << 8);
        hw |= (u64)(u8)qh << (8 * i);
        lw |= (u64)(u8)ql << (8 * i);
    }
    i8* o = qp + (size_t)row * (2 * K) + lane * V;
    if constexpr (V == 2) { *(u16*)o = (u16)hw; *(u16*)(o + K) = (u16)lw; }
    else if constexpr (V == 4) { *(u32*)o = (u32)hw; *(u32*)(o + K) = (u32)lw; }
    else { *(u64*)o = hw; *(u64*)(o + K) = lw; }
}

// ---------------- per-row i16 quantization (agg gather input) ----------------

template <int C>   // 128 or 256
__global__ __launch_bounds__(256) void k_rowquant(
    const float* __restrict__ x, short* __restrict__ qo, float* __restrict__ ds, int nrows)
{
    constexpr int V = C / 64;
    const int wave = threadIdx.x >> 6, lane = threadIdx.x & 63;
    const int row = blockIdx.x * 4 + wave;
    if (row >= nrows) return;
    const float* xr = x + (size_t)row * C + lane * V;
    float v[V];
    if (V == 2) { float2 t = *(const float2*)xr; v[0] = t.x; v[1] = t.y; }
    else        { float4 t = *(const float4*)xr; v[0] = t.x; v[1] = t.y; v[2] = t.z; v[3] = t.w; }
    float m = 0.f;
#pragma unroll
    for (int i = 0; i < V; ++i) m = fmaxf(m, fabsf(v[i]));
#pragma unroll
    for (int d = 32; d >= 1; d >>= 1) m = fmaxf(m, __shfl_xor(m, d));
    float inv = (m > 0.f) ? 32767.f / m : 0.f;
    if (lane == 0) ds[row] = (m > 0.f) ? m * (1.f / 32767.f) : 0.f;
    short* qr = qo + (size_t)row * C + lane * V;
    if (V == 2) {
        u32 wd = (u32)(u16)(short)__float2int_rn(v[0] * inv)
               | ((u32)(u16)(short)__float2int_rn(v[1] * inv) << 16);
        *(u32*)qr = wd;
    } else {
        u64 wd = 0;
#pragma unroll
        for (int i = 0; i < 4; ++i)
            wd |= (u64)(u16)(short)__float2int_rn(v[i] * inv) << (16 * i);
        *(u64*)qr = wd;
    }
}

// ---------------- aggregation over i16 rows + fused i8-split output ----------------

template <int C>   // 128 or 256
__global__ __launch_bounds__(256) void k_agg_q(
    const short* __restrict__ q, const float* __restrict__ ds,
    const int* __restrict__ offs, const int* __restrict__ csr_src,
    const float* __restrict__ csr_w, const float* __restrict__ dinv,
    i8* __restrict__ outp,         // [PADM][2C] i8 [hi(C)|lo(C)], pad rows zeroed
    float* __restrict__ dsA,       // [PADM]
    int nvalid, int padm)
{
    constexpr int NS = C / 128;     // short8 chunks per lane (1 or 2)
    const int sub = threadIdx.x >> 4;   // 0..15
    const int l = threadIdx.x & 15;
    const int node = blockIdx.x * 16 + sub;
    if (node >= padm) return;

    float acc[8 * NS];
#pragma unroll
    for (int i = 0; i < 8 * NS; ++i) acc[i] = 0.f;

    if (node < nvalid) {
        float di = dinv[node];
        float c0 = di * di * ds[node];
        const short* qn = q + (size_t)node * C + l * 8;
#pragma unroll
        for (int k = 0; k < NS; ++k) {
            s16x8 h = *(const s16x8*)(qn + k * 128);
#pragma unroll
            for (int i = 0; i < 8; ++i) acc[k * 8 + i] = c0 * (float)h[i];
        }

        int j0 = offs[node], j1 = offs[node + 1];
        int j = j0;
        for (; j + 4 <= j1; j += 4) {
            int s0 = csr_src[j],     s1 = csr_src[j + 1];
            int s2 = csr_src[j + 2], s3 = csr_src[j + 3];
            float c0e = csr_w[j]     * ds[s0];
            float c1e = csr_w[j + 1] * ds[s1];
            float c2e = csr_w[j + 2] * ds[s2];
            float c3e = csr_w[j + 3] * ds[s3];
            const short* r0 = q + (size_t)s0 * C + l * 8;
            const short* r1 = q + (size_t)s1 * C + l * 8;
            const short* r2 = q + (size_t)s2 * C + l * 8;
            const short* r3 = q + (size_t)s3 * C + l * 8;
#pragma unroll
            for (int k = 0; k < NS; ++k) {
                s16x8 h0 = *(const s16x8*)(r0 + k * 128);
                s16x8 h1 = *(const s16x8*)(r1 + k * 128);
                s16x8 h2 = *(const s16x8*)(r2 + k * 128);
                s16x8 h3 = *(const s16x8*)(r3 + k * 128);
#pragma unroll
                for (int i = 0; i < 8; ++i) {
                    acc[k * 8 + i] = fmaf(c0e, (float)h0[i], acc[k * 8 + i]);
                    acc[k * 8 + i] = fmaf(c1e, (float)h1[i], acc[k * 8 + i]);
                    acc[k * 8 + i] = fmaf(c2e, (float)h2[i], acc[k * 8 + i]);
                    acc[k * 8 + i] = fmaf(c3e, (float)h3[i], acc[k * 8 + i]);
                }
            }
        }
        for (; j < j1; ++j) {
            int s0 = csr_src[j];
            float c0e = csr_w[j] * ds[s0];
            const short* r0 = q + (size_t)s0 * C + l * 8;
#pragma unroll
            for (int k = 0; k < NS; ++k) {
                s16x8 h0 = *(const s16x8*)(r0 + k * 128);
#pragma unroll
                for (int i = 0; i < 8; ++i)
                    acc[k * 8 + i] = fmaf(c0e, (float)h0[i], acc[k * 8 + i]);
            }
        }
    }

    // fused i8-split quant: rowmax over the 16-lane group, then planes
    float m = 0.f;
#pragma unroll
    for (int i = 0; i < 8 * NS; ++i) m = fmaxf(m, fabsf(acc[i]));
#pragma unroll
    for (int d = 8; d >= 1; d >>= 1) m = fmaxf(m, __shfl_xor(m, d));
    float inv = (m > 0.f) ? 32256.f / m : 0.f;
    if (l == 0) dsA[node] = (m > 0.f) ? m * (1.f / 32256.f) : 0.f;

    i8* po = outp + (size_t)node * (2 * C);
#pragma unroll
    for (int k = 0; k < NS; ++k) {
        u64 hw = 0, lw = 0;
#pragma unroll
        for (int i = 0; i < 8; ++i) {
            int qv = __float2int_rn(acc[k * 8 + i] * inv);
            int qh = (qv + 128) >> 8;
            int ql = qv - (qh << 8);
            hw |= (u64)(u8)qh << (8 * i);
            lw |= (u64)(u8)ql << (8 * i);
        }
        int col = l * 8 + k * 128;
        *(u64*)(po + col) = hw;
        *(u64*)(po + C + col) = lw;
    }
}

// ---------------- 128-tile i8 MFMA GEMM over split-i8 operands ----------------
// A [M][2K] i8 [hi|lo], W [N][2K] i8 [hi|lo];  x = dsA*(256*Ah + Al), w = dsW*(256*Wh + Wl)
// acc1 = Ah*Wh, acc2 = Ah*Wl + Al*Wh (i32, exact); Al*Wl dropped (~1e-4 stat).
// out = dsA[r]*dsW[c]*(65536*acc1 + 256*acc2) + bias.
// EPI: 0 = relu f32, all rows; 2 = f32, row < Mvalid

template <int EPI>
__global__ __launch_bounds__(256, 2) void k_gemm_i8(
    const i8* __restrict__ A2,
    const i8* __restrict__ W2,
    const float* __restrict__ dsA,
    const float* __restrict__ dsW,
    const float* __restrict__ bias,
    float* __restrict__ Cf,
    int N, int K, int Mvalid, int nby)
{
    __shared__ i8 At[128 * 128];   // [row][ hi64 | lo64 ] per 64-k step, XOR-swizzled
    __shared__ i8 Bt[128 * 128];

    const int nwg = gridDim.x;
    const int orig = blockIdx.x;
    const int q8 = nwg >> 3, r8 = nwg & 7;
    const int xcd = orig & 7, slot = orig >> 3;
    const int L = (xcd < r8 ? xcd * (q8 + 1) : r8 * (q8 + 1) + (xcd - r8) * q8) + slot;
    const int by = L % nby;
    const int bx = L / nby;
    const int bm0 = bx * 128;
    const int bn0 = by * 128;
    const int tid = threadIdx.x;
    const int lane = tid & 63;
    const int w = tid >> 6, wr = w >> 1, wc = w & 1;
    const int g = lane >> 4, rl = lane & 15;
    const int K2 = 2 * K;

    i32x4 acc1[4][4], acc2[4][4];
#pragma unroll
    for (int i = 0; i < 4; ++i)
#pragma unroll
        for (int j = 0; j < 4; ++j) {
            acc1[i][j][0] = 0; acc1[i][j][1] = 0; acc1[i][j][2] = 0; acc1[i][j][3] = 0;
            acc2[i][j][0] = 0; acc2[i][j][1] = 0; acc2[i][j][2] = 0; acc2[i][j][3] = 0;
        }

    // staging: linear LDS dest, inverse-swizzled global source (byte granularity)
    size_t aoff[4], boff[4];
    int ldsb[4];
#pragma unroll
    for (int r = 0; r < 4; ++r) {
        int a = r * 4096 + tid * 16;        // byte in 16KB tile
        int row = a >> 7;                   // 128 B per row
        int c = a & 127;
        int cs = c ^ ((row & 7) << 4);      // logical byte col in row
        int ce = (cs < 64) ? cs : (K + (cs - 64));   // plane offset (bytes)
        aoff[r] = (size_t)(bm0 + row) * K2 + ce;
        boff[r] = (size_t)(bn0 + row) * K2 + ce;
        ldsb[r] = a;
    }

    for (int k0 = 0; k0 < K; k0 += 64) {
#pragma unroll
        for (int r = 0; r < 4; ++r) {
            __builtin_amdgcn_global_load_lds(
                (const GAS void*)(A2 + aoff[r] + k0),
                (LAS void*)(At + ldsb[r]), 16, 0, 0);
            __builtin_amdgcn_global_load_lds(
                (const GAS void*)(W2 + boff[r] + k0),
                (LAS void*)(Bt + ldsb[r]), 16, 0, 0);
        }
        __syncthreads();   // compiler drains vmcnt(0) here

        i32x4 ah[4], al[4];
#pragma unroll
        for (int m = 0; m < 4; ++m) {
            int row = wr * 64 + m * 16 + rl;
            int sw = (row & 7) << 4;
            const i8* base = At + row * 128;
            ah[m] = *(const i32x4*)(base + ((g * 16) ^ sw));
            al[m] = *(const i32x4*)(base + ((64 + g * 16) ^ sw));
        }
#pragma unroll
        for (int n = 0; n < 4; ++n) {
            int row = wc * 64 + n * 16 + rl;
            int sw = (row & 7) << 4;
            const i8* base = Bt + row * 128;
            i32x4 bh = *(const i32x4*)(base + ((g * 16) ^ sw));
            i32x4 bl = *(const i32x4*)(base + ((64 + g * 16) ^ sw));
#pragma unroll
            for (int m = 0; m < 4; ++m) {
                acc1[m][n] = __builtin_amdgcn_mfma_i32_16x16x64_i8(ah[m], bh, acc1[m][n], 0, 0, 0);
                acc2[m][n] = __builtin_amdgcn_mfma_i32_16x16x64_i8(al[m], bh, acc2[m][n], 0, 0, 0);
                acc2[m][n] = __builtin_amdgcn_mfma_i32_16x16x64_i8(ah[m], bl, acc2[m][n], 0, 0, 0);
            }
        }
        __syncthreads();
    }

    // epilogue: C/D layout col = lane&15, row = (lane>>4)*4 + reg (dtype-independent)
    float sa[4][4];
#pragma unroll
    for (int m = 0; m < 4; ++m) {
        int row0 = bm0 + wr * 64 + m * 16 + g * 4;
#pragma unroll
        for (int qq = 0; qq < 4; ++qq) sa[m][qq] = dsA[row0 + qq];
    }
#pragma unroll
    for (int n = 0; n < 4; ++n) {
        int col = bn0 + wc * 64 + n * 16 + rl;
        float sw_ = dsW[col];
        float bv = bias[col];
#pragma unroll
        for (int m = 0; m < 4; ++m) {
            int row0 = bm0 + wr * 64 + m * 16 + g * 4;
#pragma unroll
            for (int qq = 0; qq < 4; ++qq) {
                int row = row0 + qq;
                float v = sa[m][qq] * sw_ *
                          (65536.f * (float)acc1[m][n][qq] + 256.f * (float)acc2[m][n][qq]) + bv;
                if (EPI == 0) {
                    Cf[(size_t)row * N + col] = fmaxf(v, 0.f);
                } else {
                    if (row < Mvalid) Cf[(size_t)row * N + col] = v;
                }
            }
        }
    }
}

// ---------------- launch ----------------

static inline size_t align_up(size_t x, size_t a) { return (x + a - 1) & ~(a - 1); }

extern "C" void kernel_launch(void* const* d_in, const int* in_sizes, int n_in,
                              void* d_out, int out_size, void* d_ws, size_t ws_size,
                              hipStream_t stream) {
    const int*   edge_index = (const int*)d_in[0];
    const float* node = (const float*)d_in[1];
    const float* W1 = (const float*)d_in[2];
    const float* b1 = (const float*)d_in[3];
    const float* W2 = (const float*)d_in[4];
    const float* b2 = (const float*)d_in[5];
    const float* W3 = (const float*)d_in[6];
    const float* b3 = (const float*)d_in[7];
    const float* Wfc = (const float*)d_in[8];
    const float* bfc = (const float*)d_in[9];
    float* out = (float*)d_out;

    const int E = in_sizes[0] / 2;   // 400000
    const int NV = NNODES;
    const int P = PADM;

    // workspace layout
    char* ws = (char*)d_ws;
    size_t off = 0;
    int* cnt = (int*)(ws + off);          off = align_up(off + (size_t)NV * 4, 1024);
    int* offs = (int*)(ws + off);         off = align_up(off + (size_t)(NV + 1) * 4, 1024);
    int* cursor = (int*)(ws + off);       off = align_up(off + (size_t)NV * 4, 1024);
    float* dinv = (float*)(ws + off);     off = align_up(off + (size_t)NV * 4, 1024);
    int* csr_src = (int*)(ws + off);      off = align_up(off + (size_t)E * 4, 1024);
    float* csr_w = (float*)(ws + off);    off = align_up(off + (size_t)E * 4, 1024);
    i8* W1q = (i8*)(ws + off);            off = align_up(off + (size_t)128 * 256, 1024);
    i8* W2q = (i8*)(ws + off);            off = align_up(off + (size_t)256 * 256, 1024);
    i8* W3q = (i8*)(ws + off);            off = align_up(off + (size_t)512 * 512, 1024);
    i8* Wfcq = (i8*)(ws + off);           off = align_up(off + (size_t)1024 * 1024, 1024);
    float* dsW1 = (float*)(ws + off);     off = align_up(off + 128 * 4, 1024);
    float* dsW2 = (float*)(ws + off);     off = align_up(off + 256 * 4, 1024);
    float* dsW3 = (float*)(ws + off);     off = align_up(off + 512 * 4, 1024);
    float* dsWfc = (float*)(ws + off);    off = align_up(off + 1024 * 4, 1024);
    float* dsQ = (float*)(ws + off);      off = align_up(off + (size_t)P * 4, 1024);
    float* dsAgg = (float*)(ws + off);    off = align_up(off + (size_t)P * 4, 1024);
    float* dsAfc = (float*)(ws + off);    off = align_up(off + (size_t)P * 4, 1024);
    i8* A3q = (i8*)(ws + off);            off = align_up(off + (size_t)P * 512, 1024);
    i8* A4q = (i8*)(ws + off);            off = align_up(off + (size_t)P * 1024, 1024);
    // BIG overlapped region (P*2048 bytes): xbuf3 aliases {q01, A1q, xbuf1/q2, xbuf2},
    // all of which are dead by the time layer-3 GEMM writes xbuf3.
    char* big = ws + off;                 off = align_up(off + (size_t)P * 2048, 1024);
    short* q01 = (short*)big;                          // P*128 i16 = P*256 B
    i8* A1q = (i8*)(big + (size_t)P * 256);            // P*256 B
    float* xbuf1 = (float*)(big + (size_t)P * 512);    // P*128 f32 = P*512 B
    short* q2 = (short*)(big + (size_t)P * 512);       // P*256 i16 (aliases xbuf1)
    float* xbuf2 = (float*)(big + (size_t)P * 1024);   // P*256 f32 = P*1024 B
    float* xbuf3 = (float*)big;                        // P*512 f32 = P*2048 B

    const int* src = edge_index;
    const int* dst = edge_index + E;

    // weight quantization (i16 -> i8 hi/lo planes)
    k_quant_i8<128><<<(128 + 3) / 4, 256, 0, stream>>>(W1, W1q, dsW1, 128);
    k_quant_i8<128><<<(256 + 3) / 4, 256, 0, stream>>>(W2, W2q, dsW2, 256);
    k_quant_i8<256><<<(512 + 3) / 4, 256, 0, stream>>>(W3, W3q, dsW3, 512);
    k_quant_i8<512><<<(1024 + 3) / 4, 256, 0, stream>>>(Wfc, Wfcq, dsWfc, 1024);

    // CSR build
    k_zero_cnt<<<(NV + 255) / 256, 256, 0, stream>>>(cnt, NV);
    k_count<<<(E + 255) / 256, 256, 0, stream>>>(dst, E, cnt);
    k_dinv<<<(NV + 255) / 256, 256, 0, stream>>>(cnt, dinv, NV);
    k_scan<<<1, 1024, 0, stream>>>(cnt, NV, offs, cursor);
    k_fill<<<(E + 255) / 256, 256, 0, stream>>>(src, dst, E, cursor, dinv, csr_src, csr_w);

    dim3 blk(256);
    const int qGrid = (NV + 3) / 4;    // rowquant: 4 rows/block
    const int aGrid = P / 16;          // agg: 16 nodes/block
    const int nbx = P / 128;           // 392

    // layer 1: quant(node) -> q01, agg -> A1q+dsAgg, i8 gemm -> xbuf1
    k_rowquant<128><<<qGrid, blk, 0, stream>>>(node, q01, dsQ, NV);
    k_agg_q<128><<<aGrid, blk, 0, stream>>>(q01, dsQ, offs, csr_src, csr_w, dinv, A1q, dsAgg, NV, P);
    k_gemm_i8<0><<<nbx * 1, blk, 0, stream>>>(A1q, W1q, dsAgg, dsW1, b1, xbuf1, 128, 128, P, 1);

    // layer 2
    k_rowquant<128><<<qGrid, blk, 0, stream>>>(xbuf1, q01, dsQ, NV);
    k_agg_q<128><<<aGrid, blk, 0, stream>>>(q01, dsQ, offs, csr_src, csr_w, dinv, A1q, dsAgg, NV, P);
    k_gemm_i8<0><<<nbx * 2, blk, 0, stream>>>(A1q, W2q, dsAgg, dsW2, b2, xbuf2, 256, 128, P, 2);

    // layer 3 (q2 aliases xbuf1 slot; xbuf3 overwrites the whole BIG region)
    k_rowquant<256><<<qGrid, blk, 0, stream>>>(xbuf2, q2, dsQ, NV);
    k_agg_q<256><<<aGrid, blk, 0, stream>>>(q2, dsQ, offs, csr_src, csr_w, dinv, A3q, dsAgg, NV, P);
    k_gemm_i8<0><<<nbx * 4, blk, 0, stream>>>(A3q, W3q, dsAgg, dsW3, b3, xbuf3, 512, 256, P, 4);

    // FC: quantize xbuf3 rows -> A4q planes, then i8 gemm -> out (rows < NV)
    k_quant_i8<512><<<(P + 3) / 4, 256, 0, stream>>>(xbuf3, A4q, dsAfc, P);
    k_gemm_i8<2><<<nbx * 8, blk, 0, stream>>>(A4q, Wfcq, dsAfc, dsWfc, bfc, out, 1024, 512, NV, 8);
}